// Round 6
// baseline (479.294 us; speedup 1.0000x reference)
//
#include <hip/hip_runtime.h>
#include <hip/hip_bf16.h>

#define NEG_SLOPE 0.2f
#define BN_EPS 1e-5f
#define BSH 8              // bucket shift: 256 nodes per bucket
#define STASH_CAP 6400     // K4 LDS stash entries (mean ~4600, +27 sigma)

typedef __attribute__((ext_vector_type(8))) short bf16x8;
typedef __attribute__((ext_vector_type(4))) float f32x4;
typedef __attribute__((ext_vector_type(2))) float f32x2;

#if defined(__has_builtin)
#if __has_builtin(__builtin_amdgcn_cvt_f32_fp8) && __has_builtin(__builtin_amdgcn_cvt_pk_fp8_f32)
#define HW_FP8 1
#endif
#if __has_builtin(__builtin_amdgcn_cvt_pk_f32_fp8)
#define HW_FP8_PK 1
#endif
#endif

__device__ __forceinline__ float bf2f(unsigned short u) {
    union { unsigned int i; float f; } x;
    x.i = ((unsigned int)u) << 16;
    return x.f;
}
__device__ __forceinline__ unsigned short f2bf(float f) {
    __hip_bfloat16 b = __float2bfloat16(f);
    return *reinterpret_cast<unsigned short*>(&b);
}
__device__ __forceinline__ float lrelu(float v) {
    return v > 0.f ? v : NEG_SLOPE * v;
}

// ---- fp8 e4m3 (OCP) encode/decode: HW path + software fallback
__device__ __forceinline__ unsigned char f8enc(float f) {
#ifdef HW_FP8
    int p = __builtin_amdgcn_cvt_pk_fp8_f32(f, 0.f, 0, false);
    return (unsigned char)(p & 0xff);
#else
    float a = fabsf(f);
    unsigned int sign = (__float_as_uint(f) >> 31) << 7;
    if (a < 0.0009765625f) return (unsigned char)sign;
    a = fminf(a, 448.f);
    unsigned int bits = __float_as_uint(a);
    int e = (int)((bits >> 23) & 0xff) - 127;
    unsigned int mant = bits & 0x7fffff;
    if (e < -6) {
        int q = (int)(a * 512.f + 0.5f);
        if (q >= 8) return (unsigned char)(sign | 0x08);
        return (unsigned char)(sign | q);
    }
    unsigned int m = mant >> 20;
    unsigned int rem = mant & 0xfffff;
    if (rem > 0x80000 || (rem == 0x80000 && (m & 1))) m++;
    if (m == 8) { m = 0; e++; }
    if (e > 8) { e = 8; m = 6; }
    return (unsigned char)(sign | ((unsigned int)(e + 7) << 3) | m);
#endif
}
template <int SEL>
__device__ __forceinline__ float f8dec(unsigned int w) {
#ifdef HW_FP8
    return __builtin_amdgcn_cvt_f32_fp8(w, SEL);
#else
    unsigned int b = (w >> (SEL * 8)) & 0xff;
    unsigned int s = b >> 7, em = b & 0x7f;
    float mag;
    if (em >= 8) {
        unsigned int bits = (((em >> 3) + 120) << 23) | ((em & 7) << 20);
        mag = __uint_as_float(bits);
    } else {
        mag = (float)em * 0.001953125f;
    }
    return s ? -mag : mag;
#endif
}
__device__ __forceinline__ void fma_f8x4(float we, unsigned int wv, float4& acc) {
#ifdef HW_FP8_PK
    f32x2 lo = __builtin_amdgcn_cvt_pk_f32_fp8((int)wv, false);
    f32x2 hi = __builtin_amdgcn_cvt_pk_f32_fp8((int)wv, true);
    acc.x = fmaf(we, lo[0], acc.x);
    acc.y = fmaf(we, lo[1], acc.y);
    acc.z = fmaf(we, hi[0], acc.z);
    acc.w = fmaf(we, hi[1], acc.w);
#else
    acc.x = fmaf(we, f8dec<0>(wv), acc.x);
    acc.y = fmaf(we, f8dec<1>(wv), acc.y);
    acc.z = fmaf(we, f8dec<2>(wv), acc.z);
    acc.w = fmaf(we, f8dec<3>(wv), acc.w);
#endif
}

__device__ __forceinline__ int block_scan_incl(int v, int t) {
    int lane = t & 63, w = t >> 6;
    int sv = v;
    #pragma unroll
    for (int off = 1; off < 64; off <<= 1) {
        int u = __shfl_up(sv, off);
        if (lane >= off) sv += u;
    }
    __shared__ int ws_[4];
    if (lane == 63) ws_[w] = sv;
    __syncthreads();
    if (t == 0) {
        int a = 0;
        #pragma unroll
        for (int k = 0; k < 4; k++) { int x = ws_[k]; ws_[k] = a; a += x; }
    }
    __syncthreads();
    return sv + ws_[w];
}

// ================================================================ phase1: bucket histogram + prep (fused)
// blocks [0,256): bucket_count; blocks [256,...): x->bf16 + weight transposes
// + alpha weight contraction Wa[k,h] = sum_c W[k,h*32+c]*a[h,c] appended as
// extra B^T rows (so alpha comes out of the GEMM, no epilogue shfl reduce).
__global__ __launch_bounds__(256) void phase1(const int* __restrict__ dstl,
                                              int E, int N, int NB,
                                              int* __restrict__ gHist,
                                              const float* __restrict__ x,
                                              unsigned short* __restrict__ xb, int n4x,
                                              const float* __restrict__ W1,
                                              const float* __restrict__ Ws1,
                                              const float* __restrict__ W2,
                                              const float* __restrict__ Ws2,
                                              const float* __restrict__ W3,
                                              const float* __restrict__ a_src1,
                                              const float* __restrict__ a_dst1,
                                              const float* __restrict__ a_src2,
                                              const float* __restrict__ a_dst2,
                                              const float* __restrict__ a_src3,
                                              const float* __restrict__ a_dst3,
                                              unsigned short* __restrict__ Wcat1,
                                              unsigned short* __restrict__ Wcat2,
                                              unsigned short* __restrict__ W3t) {
    int t = threadIdx.x;
    if (blockIdx.x < 256) {
        __shared__ int h[256];
        h[t] = 0;
        __syncthreads();
        int Etot = E + N;
        for (int i = blockIdx.x * 256 + t; i < Etot; i += 256 * 256) {
            int d = (i < E) ? dstl[i] : (i - E);
            atomicAdd(&h[d >> BSH], 1);
        }
        __syncthreads();
        if (t < NB && h[t]) atomicAdd(&gHist[t], h[t]);
        return;
    }
    int i = (blockIdx.x - 256) * 256 + t;
    if (i < n4x) {
        float4 v = reinterpret_cast<const float4*>(x)[i];
        ushort4 o;
        o.x = f2bf(v.x); o.y = f2bf(v.y); o.z = f2bf(v.z); o.w = f2bf(v.w);
        reinterpret_cast<ushort4*>(xb)[i] = o;
        return;
    }
    int j = i - n4x;
    if (j < 32768) {
        int m = j >> 7, k = j & 127;
        Wcat1[j] = f2bf(W1[k * 256 + m]);
    } else if (j < 65536) {
        int q = j - 32768; int m = q >> 7, k = q & 127;
        Wcat1[32768 + q] = f2bf(Ws1[k * 256 + m]);
    } else if (j < 131072) {
        int q = j - 65536; int m = q >> 8, k = q & 255;
        Wcat2[q] = f2bf(W2[k * 256 + m]);
    } else if (j < 139264) {
        int q = j - 131072; int m = q >> 8, k = q & 255;
        Wcat2[65536 + q] = f2bf(Ws2[k * 32 + m]);
    } else if (j < 147456) {
        int q = j - 139264; int m = q >> 8, k = q & 255;
        W3t[q] = f2bf(W3[k * 32 + m]);
    } else if (j < 149504) {           // Wa1: rows 512..527 of Wcat1 (as|ad, 8+8)
        int q = j - 147456; int r = q >> 7, k = q & 127;
        int h = r & 7;
        const float* av = (r < 8) ? a_src1 : a_dst1;
        float s = 0.f;
        #pragma unroll
        for (int c = 0; c < 32; c++) s += W1[k * 256 + h * 32 + c] * av[h * 32 + c];
        Wcat1[(512 + r) * 128 + k] = f2bf(s);
    } else if (j < 153600) {           // Wa2: rows 288..303 of Wcat2
        int q = j - 149504; int r = q >> 8, k = q & 255;
        int h = r & 7;
        const float* av = (r < 8) ? a_src2 : a_dst2;
        float s = 0.f;
        #pragma unroll
        for (int c = 0; c < 32; c++) s += W2[k * 256 + h * 32 + c] * av[h * 32 + c];
        Wcat2[(288 + r) * 256 + k] = f2bf(s);
    } else if (j < 154112) {           // Wa3: rows 32..33 of W3t
        int q = j - 153600; int r = q >> 8, k = q & 255;
        const float* av = r ? a_dst3 : a_src3;
        float s = 0.f;
        #pragma unroll
        for (int c = 0; c < 32; c++) s += W3[k * 32 + c] * av[c];
        W3t[(32 + r) * 256 + k] = f2bf(s);
    }
}

// ================================================================ K3: bucket scatter (local scan of gHist)
__global__ __launch_bounds__(256) void bucket_scatter(const int* __restrict__ srcl,
                                                      const int* __restrict__ dstl,
                                                      int E, int N, int NB,
                                                      const int* __restrict__ gHist,
                                                      int* __restrict__ gCursor,
                                                      unsigned int* __restrict__ bktEdges) {
    __shared__ unsigned int stage[4096];
    __shared__ int lbase[256];
    __shared__ int hist[256];
    __shared__ int bexcl[257];
    __shared__ int curk[256];
    __shared__ int gbase[256];
    int t = threadIdx.x;
    int Etot = E + N;
    int begin = blockIdx.x * 4096;

    // local exclusive scan of gHist -> bucket bases
    int gv = (t < NB) ? gHist[t] : 0;
    int gincl = block_scan_incl(gv, t);
    lbase[t] = gincl - gv;
    __syncthreads();

    hist[t] = 0;
    __syncthreads();

    unsigned int ent[16];
    int eb[16];
    #pragma unroll
    for (int k = 0; k < 16; k++) {
        int i = begin + k * 256 + t;
        if (i < Etot) {
            int s, d;
            if (i < E) { s = srcl[i]; d = dstl[i]; }
            else       { s = d = i - E; }
            eb[k] = d >> BSH;
            ent[k] = ((unsigned int)s << BSH) | (unsigned int)(d & 255);
            atomicAdd(&hist[eb[k]], 1);
        } else eb[k] = -1;
    }
    __syncthreads();

    int v = hist[t];
    int incl = block_scan_incl(v, t);
    bexcl[t] = incl - v;
    curk[t] = incl - v;
    if (t == 255) bexcl[256] = incl;
    __syncthreads();

    #pragma unroll
    for (int k = 0; k < 16; k++) {
        if (eb[k] >= 0) {
            int slot = atomicAdd(&curk[eb[k]], 1);
            stage[slot] = ent[k];
        }
    }
    if (t < NB) {
        int cnt = hist[t];
        gbase[t] = cnt ? (lbase[t] + atomicAdd(&gCursor[t], cnt)) : 0;
    }
    __syncthreads();

    int total = bexcl[256];
    for (int p = t; p < total; p += 256) {
        int lo = 0, hi = NB - 1;
        while (lo < hi) {
            int mid = (lo + hi + 1) >> 1;
            if (bexcl[mid] <= p) lo = mid; else hi = mid - 1;
        }
        bktEdges[gbase[lo] + (p - bexcl[lo])] = stage[p];
    }
}

// ================================================================ K4: bucket -> fine CSR (local scan of gHist)
__global__ __launch_bounds__(256) void bucket_to_csr(const unsigned int* __restrict__ bktEdges,
                                                     const int* __restrict__ gHist,
                                                     int* __restrict__ indptr,
                                                     int* __restrict__ esrc,
                                                     int N, int NB, int Etot) {
    __shared__ int lbase[256];
    __shared__ int nh[256];
    __shared__ int ncur[256];
    __shared__ unsigned int stash[STASH_CAP];
    int b = blockIdx.x, t = threadIdx.x;

    int gv = (t < NB) ? gHist[t] : 0;
    int gincl = block_scan_incl(gv, t);
    lbase[t] = gincl - gv;
    __syncthreads();
    int base = lbase[b];
    int cnt = gHist[b];
    int nodeBase = b << BSH;

    nh[t] = 0;
    __syncthreads();
    for (int p = t; p < cnt; p += 256) {
        unsigned int e = bktEdges[base + p];
        if (p < STASH_CAP) stash[p] = e;
        atomicAdd(&nh[e & 255], 1);
    }
    __syncthreads();
    int v = nh[t];
    int incl = block_scan_incl(v, t);
    int excl = incl - v;
    ncur[t] = excl;
    if (nodeBase + t < N) indptr[nodeBase + t] = base + excl;
    __syncthreads();
    for (int p = t; p < cnt; p += 256) {
        unsigned int e = (p < STASH_CAP) ? stash[p] : bktEdges[base + p];
        int slot = atomicAdd(&ncur[e & 255], 1);
        esrc[base + slot] = (int)(e >> BSH);
    }
    if (b == 0 && t == 0) indptr[N] = Etot;
}

// ---------------------------------------------------------------- panel GEMM (M-parallel, reg-resident A)
// One block = 64 output rows; each wave owns 16 rows. A fragments for the
// wave's rows are loaded ONCE into registers (A read exactly once from HBM),
// then the wave sweeps all output columns in 128-col chunks, streaming B
// fragments from L2 (B <= 152 KB, L2-resident). Zero LDS, zero barriers,
// 8 independent MFMA chains per chunk (round-5 postmortem: the 128x128
// K-loop tile structure was latency-bound at 5% MfmaUtil for K=128..256;
// this shape wants panel decomposition, not square tiling).
// acc[8] is ONLY indexed from fully-unrolled loops (rule #20).
// Epilogue regions over output col c (all splits are 16-aligned per layer):
//   c < split           -> optional bf16 outBf, optional fp8 outQ
//   split <= c < split2 -> bf16 outSk + biasSk
//   split2 <= c < NCtot -> alpha cols: 16-wide (H=8: as|ad) or 2-wide (H=1)
template <int K>
__global__ __launch_bounds__(256) void gemm_panel(const unsigned short* __restrict__ A,
                                                  const unsigned short* __restrict__ Bt,
                                                  unsigned short* __restrict__ outBf,
                                                  unsigned char* __restrict__ outQ,
                                                  unsigned short* __restrict__ outSk,
                                                  const float* __restrict__ biasSk,
                                                  float* __restrict__ asOut,
                                                  float* __restrict__ adOut,
                                                  int M, int NCtot,
                                                  int split, int split2,
                                                  int ldBf, int ldSk) {
    constexpr int KS = K / 32;                     // MFMA k-steps
    int t = threadIdx.x;
    int w = t >> 6, lane = t & 63;
    int l16 = lane & 15, quad = lane >> 4;
    int rowBase = blockIdx.x * 64 + w * 16;        // wave's 16-row panel

    // ---- A fragments: row = rowBase + l16, k = ks*32 + quad*8 (held in regs)
    bf16x8 af[KS];
    {
        int gr = rowBase + l16; if (gr >= M) gr = M - 1;
        const unsigned short* aP = A + (size_t)gr * K + quad * 8;
        #pragma unroll
        for (int ks = 0; ks < KS; ks++)
            af[ks] = *reinterpret_cast<const bf16x8*>(aP + ks * 32);
    }

    // ---- sweep output columns in 128-col chunks (<=5 iterations)
    for (int colBase = 0; colBase < NCtot; colBase += 128) {
        f32x4 acc[8];
        #pragma unroll
        for (int j = 0; j < 8; j++) acc[j] = (f32x4){0.f, 0.f, 0.f, 0.f};

        #pragma unroll
        for (int j = 0; j < 8; j++) {
            int cc = colBase + j * 16 + l16;
            if (cc >= NCtot) cc = NCtot - 1;       // clamp; garbage cols masked at store
            const unsigned short* bP = Bt + (size_t)cc * K + quad * 8;
            #pragma unroll
            for (int ks = 0; ks < KS; ks++) {
                bf16x8 b = *reinterpret_cast<const bf16x8*>(bP + ks * 32);
                acc[j] = __builtin_amdgcn_mfma_f32_16x16x32_bf16(af[ks], b, acc[j], 0, 0, 0);
            }
        }

        // ---- epilogue for this chunk
        #pragma unroll
        for (int j = 0; j < 8; j++) {
            int c = colBase + j * 16 + l16;
            if (c >= NCtot) continue;
            if (c < split) {
                #pragma unroll
                for (int r = 0; r < 4; r++) {
                    int row = rowBase + quad * 4 + r;
                    if (row >= M) continue;
                    float v = acc[j][r];
                    if (outBf) outBf[(size_t)row * ldBf + c] = f2bf(v);
                    if (outQ)  outQ[(size_t)row * ldBf + c] = f8enc(v);
                }
            } else if (c < split2) {
                float bv = biasSk[c - split];
                #pragma unroll
                for (int r = 0; r < 4; r++) {
                    int row = rowBase + quad * 4 + r;
                    if (row >= M) continue;
                    outSk[(size_t)row * ldSk + (c - split)] = f2bf(acc[j][r] + bv);
                }
            } else {
                int a = c - split2;
                #pragma unroll
                for (int r = 0; r < 4; r++) {
                    int row = rowBase + quad * 4 + r;
                    if (row >= M) continue;
                    float v = acc[j][r];
                    if (NCtot - split2 == 16) {    // H=8: 8 as cols then 8 ad cols
                        if (a < 8) asOut[(size_t)row * 8 + a] = v;
                        else       adOut[(size_t)row * 8 + a - 8] = v;
                    } else {                       // H=1: 1 as col, 1 ad col
                        if (a == 0) asOut[row] = v;
                        else        adOut[row] = v;
                    }
                }
            }
        }
    }
}

// ---------------------------------------------------------------- aggregation H=8,C=32 (fp8 gather, dwordx4)
// Per node: one wave. Gather layout: lane l reads uint4 (16 fp8 ch) at
// channel byte (l&15)*16 of row src(e), e = 4j + (l>>4). 8-edge chunks;
// rows prefetched 1 chunk ahead, esrc/weights 2 chunks ahead.
// NOTE: accumulators are four NAMED float4 (not an array) — dynamic
// indexing sends the array to scratch (rule #20; round-2 postmortem:
// 562 MB of scratch writes).
template <int MODE>
__global__ __launch_bounds__(256) void agg256(const unsigned char* __restrict__ hq,
                                              const float* __restrict__ as,
                                              const float* __restrict__ ad,
                                              const int* __restrict__ indptr,
                                              const int* __restrict__ esrc,
                                              const float* __restrict__ bias,
                                              const float* __restrict__ bn_g,
                                              const float* __restrict__ bn_b,
                                              const float* __restrict__ bn_m,
                                              const float* __restrict__ bn_v,
                                              const unsigned short* __restrict__ skip,
                                              unsigned short* __restrict__ out, int N) {
    int t = threadIdx.x;
    int n = blockIdx.x * 4 + (t >> 6);
    if (n >= N) return;
    int lane = t & 63;
    int e8 = lane >> 3, h8 = lane & 7;   // weight-round mapping: lane = e*8 + h
    int g4 = lane >> 4, cl = lane & 15;  // gather mapping
    int hd = cl >> 1;                    // head of my gathered channels
    int start = indptr[n], end = indptr[n + 1];
    int cnt = end - start;

    float adh = ad[n * 8 + h8];
    const unsigned char* hqc = hq + cl * 16;

    float4 acc0 = make_float4(0.f, 0.f, 0.f, 0.f);
    float4 acc1 = make_float4(0.f, 0.f, 0.f, 0.f);
    float4 acc2 = make_float4(0.f, 0.f, 0.f, 0.f);
    float4 acc3 = make_float4(0.f, 0.f, 0.f, 0.f);
    float sm = 0.f;
    int nfull = cnt & ~7;

    int sA = 0, sB = 0;
    float wA = 0.f, wB = 0.f;
    uint4 hv0 = {}, hv1 = {};
    if (nfull) {
        sA = esrc[start + e8];
        wA = __expf(lrelu(as[sA * 8 + h8] + adh));
        int r0 = __shfl(sA, g4 * 8);
        int r1 = __shfl(sA, (4 + g4) * 8);
        hv0 = *reinterpret_cast<const uint4*>(hqc + (size_t)r0 * 256);
        hv1 = *reinterpret_cast<const uint4*>(hqc + (size_t)r1 * 256);
        if (nfull > 8) {
            sB = esrc[start + 8 + e8];
            wB = __expf(lrelu(as[sB * 8 + h8] + adh));
        }
    }
    for (int i0 = start; i0 < start + nfull; i0 += 8) {
        uint4 u0 = hv0, u1 = hv1;
        float wcur = wA;
        // prefetch next chunk's rows (srcs sB already resident)
        if (i0 + 8 < start + nfull) {
            int r0 = __shfl(sB, g4 * 8);
            int r1 = __shfl(sB, (4 + g4) * 8);
            hv0 = *reinterpret_cast<const uint4*>(hqc + (size_t)r0 * 256);
            hv1 = *reinterpret_cast<const uint4*>(hqc + (size_t)r1 * 256);
        }
        // shift weight pipeline, prefetch srcs/weights 2 chunks ahead
        sA = sB; wA = wB;
        if (i0 + 16 < start + nfull) {
            sB = esrc[i0 + 16 + e8];
            wB = __expf(lrelu(as[sB * 8 + h8] + adh));
        }
        sm += wcur;
        float w0 = __shfl(wcur, g4 * 8 + hd);
        float w1 = __shfl(wcur, (4 + g4) * 8 + hd);
        fma_f8x4(w0, u0.x, acc0);
        fma_f8x4(w0, u0.y, acc1);
        fma_f8x4(w0, u0.z, acc2);
        fma_f8x4(w0, u0.w, acc3);
        fma_f8x4(w1, u1.x, acc0);
        fma_f8x4(w1, u1.y, acc1);
        fma_f8x4(w1, u1.z, acc2);
        fma_f8x4(w1, u1.w, acc3);
    }
    int rem = cnt - nfull;
    if (rem) {
        int i0 = start + nfull;
        int idx = i0 + e8;
        bool valid = idx < end;
        int s_r = esrc[valid ? idx : end - 1];
        float w_r = valid ? __expf(lrelu(as[s_r * 8 + h8] + adh)) : 0.f;
        sm += w_r;
        int r0 = __shfl(s_r, g4 * 8);                     // clamped rows (cache-hot)
        uint4 u0 = *reinterpret_cast<const uint4*>(hqc + (size_t)r0 * 256);
        float w0 = __shfl(w_r, g4 * 8 + hd);              // 0 for padded edges
        fma_f8x4(w0, u0.x, acc0);
        fma_f8x4(w0, u0.y, acc1);
        fma_f8x4(w0, u0.z, acc2);
        fma_f8x4(w0, u0.w, acc3);
        if (rem > 4) {
            int r1 = __shfl(s_r, (4 + g4) * 8);
            uint4 u1 = *reinterpret_cast<const uint4*>(hqc + (size_t)r1 * 256);
            float w1 = __shfl(w_r, (4 + g4) * 8 + hd);
            fma_f8x4(w1, u1.x, acc0);
            fma_f8x4(w1, u1.y, acc1);
            fma_f8x4(w1, u1.z, acc2);
            fma_f8x4(w1, u1.w, acc3);
        }
    }

    // combine the 4 edge-groups (all groups hold the same 16 channels)
    acc0.x += __shfl_xor(acc0.x, 16); acc0.y += __shfl_xor(acc0.y, 16);
    acc0.z += __shfl_xor(acc0.z, 16); acc0.w += __shfl_xor(acc0.w, 16);
    acc0.x += __shfl_xor(acc0.x, 32); acc0.y += __shfl_xor(acc0.y, 32);
    acc0.z += __shfl_xor(acc0.z, 32); acc0.w += __shfl_xor(acc0.w, 32);
    acc1.x += __shfl_xor(acc1.x, 16); acc1.y += __shfl_xor(acc1.y, 16);
    acc1.z += __shfl_xor(acc1.z, 16); acc1.w += __shfl_xor(acc1.w, 16);
    acc1.x += __shfl_xor(acc1.x, 32); acc1.y += __shfl_xor(acc1.y, 32);
    acc1.z += __shfl_xor(acc1.z, 32); acc1.w += __shfl_xor(acc1.w, 32);
    acc2.x += __shfl_xor(acc2.x, 16); acc2.y += __shfl_xor(acc2.y, 16);
    acc2.z += __shfl_xor(acc2.z, 16); acc2.w += __shfl_xor(acc2.w, 16);
    acc2.x += __shfl_xor(acc2.x, 32); acc2.y += __shfl_xor(acc2.y, 32);
    acc2.z += __shfl_xor(acc2.z, 32); acc2.w += __shfl_xor(acc2.w, 32);
    acc3.x += __shfl_xor(acc3.x, 16); acc3.y += __shfl_xor(acc3.y, 16);
    acc3.z += __shfl_xor(acc3.z, 16); acc3.w += __shfl_xor(acc3.w, 16);
    acc3.x += __shfl_xor(acc3.x, 32); acc3.y += __shfl_xor(acc3.y, 32);
    acc3.z += __shfl_xor(acc3.z, 32); acc3.w += __shfl_xor(acc3.w, 32);

    // per-head softmax denominators
    #pragma unroll
    for (int off = 8; off < 64; off <<= 1) sm += __shfl_xor(sm, off);
    float il = 1.f / (sm + 1e-16f);
    float il_c = __shfl(il, hd);

    // lane stores channel quarter cb = cl*16 + g4*4 (same head hd).
    // if/else over NAMED vars -> v_cndmask, no stack array.
    float4 my;
    if (g4 == 0)      my = acc0;
    else if (g4 == 1) my = acc1;
    else if (g4 == 2) my = acc2;
    else              my = acc3;
    int cb = cl * 16 + g4 * 4;

    float4 bv  = *reinterpret_cast<const float4*>(&bias[cb]);
    float4 gv  = *reinterpret_cast<const float4*>(&bn_g[cb]);
    float4 bbv = *reinterpret_cast<const float4*>(&bn_b[cb]);
    float4 mv  = *reinterpret_cast<const float4*>(&bn_m[cb]);
    float4 vv  = *reinterpret_cast<const float4*>(&bn_v[cb]);
    float o[4] = {my.x * il_c + bv.x, my.y * il_c + bv.y,
                  my.z * il_c + bv.z, my.w * il_c + bv.w};
    float g[4] = {gv.x, gv.y, gv.z, gv.w}, bb[4] = {bbv.x, bbv.y, bbv.z, bbv.w};
    float m[4] = {mv.x, mv.y, mv.z, mv.w}, vr[4] = {vv.x, vv.y, vv.z, vv.w};
    float sk[4] = {0.f, 0.f, 0.f, 0.f};
    if (MODE == 1) {
        ushort4 s4 = *reinterpret_cast<const ushort4*>(&skip[(size_t)n * 256 + cb]);
        sk[0] = bf2f(s4.x); sk[1] = bf2f(s4.y); sk[2] = bf2f(s4.z); sk[3] = bf2f(s4.w);
    }
    ushort4 res;
    unsigned short* rp = &res.x;
    #pragma unroll
    for (int j = 0; j < 4; j++) {
        float val = (o[j] - m[j]) * rsqrtf(vr[j] + BN_EPS) * g[j] + bb[j];
        val = val > 0.f ? val : (__expf(val) - 1.f);
        val += sk[j];
        rp[j] = f2bf(val);
    }
    *reinterpret_cast<ushort4*>(&out[(size_t)n * 256 + cb]) = res;
}

// ---------------------------------------------------------------- aggregation H=1,C=32
__global__ __launch_bounds__(256) void agg32(const unsigned short* __restrict__ h3,
                                             const float* __restrict__ as,
                                             const float* __restrict__ ad,
                                             const int* __restrict__ indptr,
                                             const int* __restrict__ esrc,
                                             const float* __restrict__ b3,
                                             const unsigned short* __restrict__ xs,
                                             float* __restrict__ out, int N) {
    int t = threadIdx.x;
    int n = blockIdx.x * 4 + (t >> 6);
    if (n >= N) return;
    int lane = t & 63;
    int e_sub = lane >> 3, c4 = (lane & 7) * 4;
    int start = indptr[n], end = indptr[n + 1];
    float adn = ad[n];

    float4 acc = make_float4(0.f, 0.f, 0.f, 0.f);
    float sm = 0.f;
    int i0 = start;
    for (; i0 + 16 <= end; i0 += 16) {
        int sA = esrc[i0 + e_sub];
        int sB = esrc[i0 + 8 + e_sub];
        float wA = __expf(lrelu(as[sA] + adn));
        float wB = __expf(lrelu(as[sB] + adn));
        sm += wA + wB;
        ushort4 hA = *reinterpret_cast<const ushort4*>(&h3[(size_t)sA * 32 + c4]);
        ushort4 hB = *reinterpret_cast<const ushort4*>(&h3[(size_t)sB * 32 + c4]);
        acc.x = fmaf(wA, bf2f(hA.x), acc.x); acc.y = fmaf(wA, bf2f(hA.y), acc.y);
        acc.z = fmaf(wA, bf2f(hA.z), acc.z); acc.w = fmaf(wA, bf2f(hA.w), acc.w);
        acc.x = fmaf(wB, bf2f(hB.x), acc.x); acc.y = fmaf(wB, bf2f(hB.y), acc.y);
        acc.z = fmaf(wB, bf2f(hB.z), acc.z); acc.w = fmaf(wB, bf2f(hB.w), acc.w);
    }
    for (; i0 < end; i0 += 8) {
        int idx = i0 + e_sub;
        bool valid = idx < end;
        if (valid) {
            int s = esrc[idx];
            float w = __expf(lrelu(as[s] + adn));
            sm += w;
            ushort4 hv = *reinterpret_cast<const ushort4*>(&h3[(size_t)s * 32 + c4]);
            acc.x = fmaf(w, bf2f(hv.x), acc.x);
            acc.y = fmaf(w, bf2f(hv.y), acc.y);
            acc.z = fmaf(w, bf2f(hv.z), acc.z);
            acc.w = fmaf(w, bf2f(hv.w), acc.w);
        }
    }
    #pragma unroll
    for (int off = 8; off < 64; off <<= 1) {
        sm    += __shfl_xor(sm, off);
        acc.x += __shfl_xor(acc.x, off);
        acc.y += __shfl_xor(acc.y, off);
        acc.z += __shfl_xor(acc.z, off);
        acc.w += __shfl_xor(acc.w, off);
    }
    if (e_sub == 0) {
        float il = 1.f / (sm + 1e-16f);
        float4 bv = *reinterpret_cast<const float4*>(&b3[c4]);
        ushort4 xv = *reinterpret_cast<const ushort4*>(&xs[(size_t)n * 32 + c4]);
        float4 o;
        o.x = acc.x * il + bv.x + bf2f(xv.x);
        o.y = acc.y * il + bv.y + bf2f(xv.y);
        o.z = acc.z * il + bv.z + bf2f(xv.z);
        o.w = acc.w * il + bv.w + bf2f(xv.w);
        *reinterpret_cast<float4*>(&out[(size_t)n * 32 + c4]) = o;
    }
}

// ---------------------------------------------------------------- launch
extern "C" void kernel_launch(void* const* d_in, const int* in_sizes, int n_in,
                              void* d_out, int out_size, void* d_ws, size_t ws_size,
                              hipStream_t stream) {
    const float* x      = (const float*)d_in[0];
    const int*   eidx   = (const int*)  d_in[1];
    const float* W1     = (const float*)d_in[2];
    const float* a_src1 = (const float*)d_in[3];
    const float* a_dst1 = (const float*)d_in[4];
    const float* b1     = (const float*)d_in[5];
    const float* bn1_g  = (const float*)d_in[6];
    const float* bn1_b  = (const float*)d_in[7];
    const float* bn1_m  = (const float*)d_in[8];
    const float* bn1_v  = (const float*)d_in[9];
    const float* W2     = (const float*)d_in[10];
    const float* a_src2 = (const float*)d_in[11];
    const float* a_dst2 = (const float*)d_in[12];
    const float* b2     = (const float*)d_in[13];
    const float* bn2_g  = (const float*)d_in[14];
    const float* bn2_b  = (const float*)d_in[15];
    const float* bn2_m  = (const float*)d_in[16];
    const float* bn2_v  = (const float*)d_in[17];
    const float* W3     = (const float*)d_in[18];
    const float* a_src3 = (const float*)d_in[19];
    const float* a_dst3 = (const float*)d_in[20];
    const float* b3     = (const float*)d_in[21];
    const float* Ws1    = (const float*)d_in[22];
    const float* bs1    = (const float*)d_in[23];
    const float* Ws2    = (const float*)d_in[24];
    const float* bs2    = (const float*)d_in[25];

    const int N = in_sizes[0] / 128;   // 50000
    const int E = in_sizes[1] / 2;     // 800000
    const int Etot = E + N;
    const int NB = (N + 255) >> 8;     // 196 buckets
    const int* srcl = eidx;
    const int* dstl = eidx + E;

    char* ws = (char*)d_ws;
    size_t off = 0;
    auto alloc = [&](size_t bytes) -> void* {
        void* p = ws + off;
        off += (bytes + 255) & ~(size_t)255;
        return p;
    };
    unsigned short* xb    = (unsigned short*)alloc((size_t)N * 128 * 2);
    unsigned short* feat  = (unsigned short*)alloc((size_t)N * 256 * 2); // x0 skip (bf16)
    unsigned char*  hq    = (unsigned char*)alloc((size_t)N * 256);     // fp8 h for gathers
    unsigned short* h2b   = (unsigned short*)alloc((size_t)N * 256 * 2); // layer-1 agg out
    unsigned short* featb = (unsigned short*)alloc((size_t)N * 256 * 2); // layer-2 agg out
    unsigned short* xsbuf = (unsigned short*)alloc((size_t)N * 32 * 2);  // xs skip (bf16)
    unsigned short* h3b   = (unsigned short*)alloc((size_t)N * 32 * 2);
    float*          asb   = (float*)alloc((size_t)N * 8 * 4);
    float*          adb   = (float*)alloc((size_t)N * 8 * 4);
    unsigned short* Wcat1 = (unsigned short*)alloc((size_t)528 * 128 * 2); // [W1t; Ws1t; Wa1]
    unsigned short* Wcat2 = (unsigned short*)alloc((size_t)304 * 256 * 2); // [W2t; Ws2t; Wa2]
    unsigned short* W3t   = (unsigned short*)alloc((size_t)34 * 256 * 2);  // [W3t; Wa3]
    int* gHC     = (int*)alloc(512 * 4);          // [gHist(256) | gCursor(256)]
    int* gHist   = gHC;
    int* gCursor = gHC + 256;
    unsigned int* bktEdges = (unsigned int*)alloc((size_t)Etot * 4);
    int* indptr  = (int*)alloc((size_t)(N + 1) * 4);
    int* esrc    = (int*)alloc((size_t)Etot * 4);
    (void)ws_size; (void)n_in; (void)out_size;

    // ---- CSR build (bucketed multi-split, scans recomputed locally)
    hipMemsetAsync(gHC, 0, 512 * 4, stream);
    int n4x = N * 128 / 4;
    int prepBlocks = (n4x + 154112 + 255) / 256;
    phase1<<<256 + prepBlocks, 256, 0, stream>>>(dstl, E, N, NB, gHist,
                                                 x, xb, n4x,
                                                 W1, Ws1, W2, Ws2, W3,
                                                 a_src1, a_dst1, a_src2, a_dst2,
                                                 a_src3, a_dst3,
                                                 Wcat1, Wcat2, W3t);
    bucket_scatter<<<(Etot + 4095) / 4096, 256, 0, stream>>>(srcl, dstl, E, N, NB,
                                                             gHist, gCursor, bktEdges);
    bucket_to_csr<<<NB, 256, 0, stream>>>(bktEdges, gHist, indptr, esrc, N, NB, Etot);

    int gy64 = (N + 63) / 64;          // 782 panel blocks
    int gn4 = (N + 3) / 4;

    // ---- layer 1: fused [h1 | x0 | alpha] = x @ [W1 | Ws1 | Wa1]
    gemm_panel<128><<<gy64, 256, 0, stream>>>(xb, Wcat1, nullptr, hq, feat, bs1,
                                              asb, adb,
                                              N, 528, 256, 512, 256, 256);
    agg256<1><<<gn4, 256, 0, stream>>>(hq, asb, adb, indptr, esrc, b1,
                                       bn1_g, bn1_b, bn1_m, bn1_v, feat, h2b, N);

    // ---- layer 2: fused [h2 | xs | alpha] = h @ [W2 | Ws2 | Wa2]
    gemm_panel<256><<<gy64, 256, 0, stream>>>(h2b, Wcat2, nullptr, hq, xsbuf, bs2,
                                              asb, adb,
                                              N, 304, 256, 288, 256, 32);
    agg256<0><<<gn4, 256, 0, stream>>>(hq, asb, adb, indptr, esrc, b2,
                                       bn2_g, bn2_b, bn2_m, bn2_v, nullptr, featb, N);

    // ---- layer 3: [h3 | alpha] = featb @ [W3t | Wa3]  (H=1)
    gemm_panel<256><<<gy64, 256, 0, stream>>>(featb, W3t, h3b, nullptr, nullptr, nullptr,
                                              asb, adb,
                                              N, 34, 32, 32, 32, 32);
    agg32<<<gn4, 256, 0, stream>>>(h3b, asb, adb, indptr, esrc, b3, xsbuf,
                                   (float*)d_out, N);
}

// Round 7
// 348.639 us; speedup vs baseline: 1.3748x; 1.3748x over previous
//
#include <hip/hip_runtime.h>
#include <hip/hip_bf16.h>

#define NEG_SLOPE 0.2f
#define BN_EPS 1e-5f
#define BSH 8              // bucket shift: 256 nodes per bucket
#define STASH_CAP 6400     // K4 LDS stash entries (mean ~4600, +27 sigma)

typedef __attribute__((ext_vector_type(8))) short bf16x8;
typedef __attribute__((ext_vector_type(4))) float f32x4;
typedef __attribute__((ext_vector_type(2))) float f32x2;

#if defined(__has_builtin)
#if __has_builtin(__builtin_amdgcn_cvt_f32_fp8) && __has_builtin(__builtin_amdgcn_cvt_pk_fp8_f32)
#define HW_FP8 1
#endif
#if __has_builtin(__builtin_amdgcn_cvt_pk_f32_fp8)
#define HW_FP8_PK 1
#endif
#endif

__device__ __forceinline__ float bf2f(unsigned short u) {
    union { unsigned int i; float f; } x;
    x.i = ((unsigned int)u) << 16;
    return x.f;
}
__device__ __forceinline__ unsigned short f2bf(float f) {
    __hip_bfloat16 b = __float2bfloat16(f);
    return *reinterpret_cast<unsigned short*>(&b);
}
__device__ __forceinline__ float lrelu(float v) {
    return v > 0.f ? v : NEG_SLOPE * v;
}
__device__ __forceinline__ void gload_lds16(const void* g, void* l) {
    __builtin_amdgcn_global_load_lds(
        (const __attribute__((address_space(1))) unsigned int*)(g),
        (__attribute__((address_space(3))) unsigned int*)(l),
        16, 0, 0);
}

// ---- fp8 e4m3 (OCP) encode/decode: HW path + software fallback
__device__ __forceinline__ unsigned char f8enc(float f) {
#ifdef HW_FP8
    int p = __builtin_amdgcn_cvt_pk_fp8_f32(f, 0.f, 0, false);
    return (unsigned char)(p & 0xff);
#else
    float a = fabsf(f);
    unsigned int sign = (__float_as_uint(f) >> 31) << 7;
    if (a < 0.0009765625f) return (unsigned char)sign;
    a = fminf(a, 448.f);
    unsigned int bits = __float_as_uint(a);
    int e = (int)((bits >> 23) & 0xff) - 127;
    unsigned int mant = bits & 0x7fffff;
    if (e < -6) {
        int q = (int)(a * 512.f + 0.5f);
        if (q >= 8) return (unsigned char)(sign | 0x08);
        return (unsigned char)(sign | q);
    }
    unsigned int m = mant >> 20;
    unsigned int rem = mant & 0xfffff;
    if (rem > 0x80000 || (rem == 0x80000 && (m & 1))) m++;
    if (m == 8) { m = 0; e++; }
    if (e > 8) { e = 8; m = 6; }
    return (unsigned char)(sign | ((unsigned int)(e + 7) << 3) | m);
#endif
}
template <int SEL>
__device__ __forceinline__ float f8dec(unsigned int w) {
#ifdef HW_FP8
    return __builtin_amdgcn_cvt_f32_fp8(w, SEL);
#else
    unsigned int b = (w >> (SEL * 8)) & 0xff;
    unsigned int s = b >> 7, em = b & 0x7f;
    float mag;
    if (em >= 8) {
        unsigned int bits = (((em >> 3) + 120) << 23) | ((em & 7) << 20);
        mag = __uint_as_float(bits);
    } else {
        mag = (float)em * 0.001953125f;
    }
    return s ? -mag : mag;
#endif
}
__device__ __forceinline__ void fma_f8x4(float we, unsigned int wv, float4& acc) {
#ifdef HW_FP8_PK
    f32x2 lo = __builtin_amdgcn_cvt_pk_f32_fp8((int)wv, false);
    f32x2 hi = __builtin_amdgcn_cvt_pk_f32_fp8((int)wv, true);
    acc.x = fmaf(we, lo[0], acc.x);
    acc.y = fmaf(we, lo[1], acc.y);
    acc.z = fmaf(we, hi[0], acc.z);
    acc.w = fmaf(we, hi[1], acc.w);
#else
    acc.x = fmaf(we, f8dec<0>(wv), acc.x);
    acc.y = fmaf(we, f8dec<1>(wv), acc.y);
    acc.z = fmaf(we, f8dec<2>(wv), acc.z);
    acc.w = fmaf(we, f8dec<3>(wv), acc.w);
#endif
}

__device__ __forceinline__ int block_scan_incl(int v, int t) {
    int lane = t & 63, w = t >> 6;
    int sv = v;
    #pragma unroll
    for (int off = 1; off < 64; off <<= 1) {
        int u = __shfl_up(sv, off);
        if (lane >= off) sv += u;
    }
    __shared__ int ws_[4];
    if (lane == 63) ws_[w] = sv;
    __syncthreads();
    if (t == 0) {
        int a = 0;
        #pragma unroll
        for (int k = 0; k < 4; k++) { int x = ws_[k]; ws_[k] = a; a += x; }
    }
    __syncthreads();
    return sv + ws_[w];
}

// ================================================================ phase1: bucket histogram + prep (fused)
// blocks [0,256): bucket_count; blocks [256,...): x->bf16 + weight transposes
// + alpha weight contraction Wa[k,h] = sum_c W[k,h*32+c]*a[h,c] appended as
// extra B^T rows (so alpha comes out of the GEMM, no epilogue shfl reduce).
__global__ __launch_bounds__(256) void phase1(const int* __restrict__ dstl,
                                              int E, int N, int NB,
                                              int* __restrict__ gHist,
                                              const float* __restrict__ x,
                                              unsigned short* __restrict__ xb, int n4x,
                                              const float* __restrict__ W1,
                                              const float* __restrict__ Ws1,
                                              const float* __restrict__ W2,
                                              const float* __restrict__ Ws2,
                                              const float* __restrict__ W3,
                                              const float* __restrict__ a_src1,
                                              const float* __restrict__ a_dst1,
                                              const float* __restrict__ a_src2,
                                              const float* __restrict__ a_dst2,
                                              const float* __restrict__ a_src3,
                                              const float* __restrict__ a_dst3,
                                              unsigned short* __restrict__ Wcat1,
                                              unsigned short* __restrict__ Wcat2,
                                              unsigned short* __restrict__ W3t) {
    int t = threadIdx.x;
    if (blockIdx.x < 256) {
        __shared__ int h[256];
        h[t] = 0;
        __syncthreads();
        int Etot = E + N;
        for (int i = blockIdx.x * 256 + t; i < Etot; i += 256 * 256) {
            int d = (i < E) ? dstl[i] : (i - E);
            atomicAdd(&h[d >> BSH], 1);
        }
        __syncthreads();
        if (t < NB && h[t]) atomicAdd(&gHist[t], h[t]);
        return;
    }
    int i = (blockIdx.x - 256) * 256 + t;
    if (i < n4x) {
        float4 v = reinterpret_cast<const float4*>(x)[i];
        ushort4 o;
        o.x = f2bf(v.x); o.y = f2bf(v.y); o.z = f2bf(v.z); o.w = f2bf(v.w);
        reinterpret_cast<ushort4*>(xb)[i] = o;
        return;
    }
    int j = i - n4x;
    if (j < 32768) {
        int m = j >> 7, k = j & 127;
        Wcat1[j] = f2bf(W1[k * 256 + m]);
    } else if (j < 65536) {
        int q = j - 32768; int m = q >> 7, k = q & 127;
        Wcat1[32768 + q] = f2bf(Ws1[k * 256 + m]);
    } else if (j < 131072) {
        int q = j - 65536; int m = q >> 8, k = q & 255;
        Wcat2[q] = f2bf(W2[k * 256 + m]);
    } else if (j < 139264) {
        int q = j - 131072; int m = q >> 8, k = q & 255;
        Wcat2[65536 + q] = f2bf(Ws2[k * 32 + m]);
    } else if (j < 147456) {
        int q = j - 139264; int m = q >> 8, k = q & 255;
        W3t[q] = f2bf(W3[k * 32 + m]);
    } else if (j < 149504) {           // Wa1: rows 512..527 of Wcat1 (as|ad, 8+8)
        int q = j - 147456; int r = q >> 7, k = q & 127;
        int h = r & 7;
        const float* av = (r < 8) ? a_src1 : a_dst1;
        float s = 0.f;
        #pragma unroll
        for (int c = 0; c < 32; c++) s += W1[k * 256 + h * 32 + c] * av[h * 32 + c];
        Wcat1[(512 + r) * 128 + k] = f2bf(s);
    } else if (j < 153600) {           // Wa2: rows 288..303 of Wcat2
        int q = j - 149504; int r = q >> 8, k = q & 255;
        int h = r & 7;
        const float* av = (r < 8) ? a_src2 : a_dst2;
        float s = 0.f;
        #pragma unroll
        for (int c = 0; c < 32; c++) s += W2[k * 256 + h * 32 + c] * av[h * 32 + c];
        Wcat2[(288 + r) * 256 + k] = f2bf(s);
    } else if (j < 154112) {           // Wa3: rows 32..33 of W3t
        int q = j - 153600; int r = q >> 8, k = q & 255;
        const float* av = r ? a_dst3 : a_src3;
        float s = 0.f;
        #pragma unroll
        for (int c = 0; c < 32; c++) s += W3[k * 32 + c] * av[c];
        W3t[(32 + r) * 256 + k] = f2bf(s);
    }
}

// ================================================================ K3: bucket scatter (local scan of gHist)
__global__ __launch_bounds__(256) void bucket_scatter(const int* __restrict__ srcl,
                                                      const int* __restrict__ dstl,
                                                      int E, int N, int NB,
                                                      const int* __restrict__ gHist,
                                                      int* __restrict__ gCursor,
                                                      unsigned int* __restrict__ bktEdges) {
    __shared__ unsigned int stage[4096];
    __shared__ int lbase[256];
    __shared__ int hist[256];
    __shared__ int bexcl[257];
    __shared__ int curk[256];
    __shared__ int gbase[256];
    int t = threadIdx.x;
    int Etot = E + N;
    int begin = blockIdx.x * 4096;

    // local exclusive scan of gHist -> bucket bases
    int gv = (t < NB) ? gHist[t] : 0;
    int gincl = block_scan_incl(gv, t);
    lbase[t] = gincl - gv;
    __syncthreads();

    hist[t] = 0;
    __syncthreads();

    unsigned int ent[16];
    int eb[16];
    #pragma unroll
    for (int k = 0; k < 16; k++) {
        int i = begin + k * 256 + t;
        if (i < Etot) {
            int s, d;
            if (i < E) { s = srcl[i]; d = dstl[i]; }
            else       { s = d = i - E; }
            eb[k] = d >> BSH;
            ent[k] = ((unsigned int)s << BSH) | (unsigned int)(d & 255);
            atomicAdd(&hist[eb[k]], 1);
        } else eb[k] = -1;
    }
    __syncthreads();

    int v = hist[t];
    int incl = block_scan_incl(v, t);
    bexcl[t] = incl - v;
    curk[t] = incl - v;
    if (t == 255) bexcl[256] = incl;
    __syncthreads();

    #pragma unroll
    for (int k = 0; k < 16; k++) {
        if (eb[k] >= 0) {
            int slot = atomicAdd(&curk[eb[k]], 1);
            stage[slot] = ent[k];
        }
    }
    if (t < NB) {
        int cnt = hist[t];
        gbase[t] = cnt ? (lbase[t] + atomicAdd(&gCursor[t], cnt)) : 0;
    }
    __syncthreads();

    int total = bexcl[256];
    for (int p = t; p < total; p += 256) {
        int lo = 0, hi = NB - 1;
        while (lo < hi) {
            int mid = (lo + hi + 1) >> 1;
            if (bexcl[mid] <= p) lo = mid; else hi = mid - 1;
        }
        bktEdges[gbase[lo] + (p - bexcl[lo])] = stage[p];
    }
}

// ================================================================ K4: bucket -> fine CSR (local scan of gHist)
__global__ __launch_bounds__(256) void bucket_to_csr(const unsigned int* __restrict__ bktEdges,
                                                     const int* __restrict__ gHist,
                                                     int* __restrict__ indptr,
                                                     int* __restrict__ esrc,
                                                     int N, int NB, int Etot) {
    __shared__ int lbase[256];
    __shared__ int nh[256];
    __shared__ int ncur[256];
    __shared__ unsigned int stash[STASH_CAP];
    int b = blockIdx.x, t = threadIdx.x;

    int gv = (t < NB) ? gHist[t] : 0;
    int gincl = block_scan_incl(gv, t);
    lbase[t] = gincl - gv;
    __syncthreads();
    int base = lbase[b];
    int cnt = gHist[b];
    int nodeBase = b << BSH;

    nh[t] = 0;
    __syncthreads();
    for (int p = t; p < cnt; p += 256) {
        unsigned int e = bktEdges[base + p];
        if (p < STASH_CAP) stash[p] = e;
        atomicAdd(&nh[e & 255], 1);
    }
    __syncthreads();
    int v = nh[t];
    int incl = block_scan_incl(v, t);
    int excl = incl - v;
    ncur[t] = excl;
    if (nodeBase + t < N) indptr[nodeBase + t] = base + excl;
    __syncthreads();
    for (int p = t; p < cnt; p += 256) {
        unsigned int e = (p < STASH_CAP) ? stash[p] : bktEdges[base + p];
        int slot = atomicAdd(&ncur[e & 255], 1);
        esrc[base + slot] = (int)(e >> BSH);
    }
    if (b == 0 && t == 0) indptr[N] = Etot;
}

// ---------------------------------------------------------------- panel GEMM: A in regs, B chunk in LDS
// Grid = (M/64 panels, col chunks of COLS). Block stages its 32 KB B chunk
// into LDS ONCE via global_load_lds (L2-broadcast across panel blocks),
// single barrier, then pure ds_read_b128 + MFMA (compiler emits fine
// lgkmcnt). Round-6 postmortem: per-wave B streaming from L2 serialized
// load->mfma at ~200cy each (VALU 4%, Mfma 3.7%); B must be fetched once
// per block into short-latency storage.
// LDS XOR swizzle, rule #21 both-sides: linear LDS dest; staging source
// byte = a ^ ((a>>RB & 15)<<4); ds_read addr gets the same XOR. 2-way
// conflict residual (free, m136).
// acc[] / af[] only indexed from fully-unrolled loops (rule #20).
// Epilogue regions over output col c (all splits 16-aligned):
//   c < split           -> optional bf16 outBf, optional fp8 outQ
//   split <= c < split2 -> bf16 outSk + biasSk
//   split2 <= c < NCtot -> alpha cols: 16-wide (H=8: as|ad) or 2-wide (H=1)
// Bt must be padded to gridDim.y*COLS columns (pad cols masked at store).
template <int K, int COLS>
__global__ __launch_bounds__(256) void gemm_panel(const unsigned short* __restrict__ A,
                                                  const unsigned short* __restrict__ Bt,
                                                  unsigned short* __restrict__ outBf,
                                                  unsigned char* __restrict__ outQ,
                                                  unsigned short* __restrict__ outSk,
                                                  const float* __restrict__ biasSk,
                                                  float* __restrict__ asOut,
                                                  float* __restrict__ adOut,
                                                  int M, int NCtot,
                                                  int split, int split2,
                                                  int ldBf, int ldSk) {
    constexpr int KS = K / 32;                 // MFMA k-steps
    constexpr int NJ = COLS / 16;              // 16-col fragments per chunk
    constexpr int BYTES = COLS * K * 2;        // 32768 for all instantiations
    constexpr int RB = (K == 128) ? 8 : 9;     // log2(row bytes)
    __shared__ __align__(16) char lds[BYTES];

    int t = threadIdx.x;
    int w = t >> 6, lane = t & 63;
    int l16 = lane & 15, quad = lane >> 4;
    int rowBase = blockIdx.x * 64 + w * 16;    // wave's 16-row panel
    int colBase = blockIdx.y * COLS;

    // ---- A fragments: row = rowBase + l16, k = ks*32 + quad*8 (regs, once)
    bf16x8 af[KS];
    {
        int gr = rowBase + l16; if (gr >= M) gr = M - 1;
        const unsigned short* aP = A + (size_t)gr * K + quad * 8;
        #pragma unroll
        for (int ks = 0; ks < KS; ks++)
            af[ks] = *reinterpret_cast<const bf16x8*>(aP + ks * 32);
    }

    // ---- stage B chunk -> LDS, source pre-XOR'd (involution; row bits >= RB
    //      unaffected by the XOR so row(a)==row(g))
    {
        const char* bSrc = reinterpret_cast<const char*>(Bt + (size_t)colBase * K);
        #pragma unroll
        for (int i = 0; i < BYTES / 4096; i++) {
            int a = (i * 256 + t) * 16;
            int g = a ^ (((a >> RB) & 15) << 4);
            gload_lds16(bSrc + g, &lds[a]);
        }
    }
    __syncthreads();

    // ---- compute: NJ independent MFMA chains, B frags from LDS (swizzled)
    f32x4 acc[NJ];
    #pragma unroll
    for (int j = 0; j < NJ; j++) acc[j] = (f32x4){0.f, 0.f, 0.f, 0.f};

    #pragma unroll
    for (int j = 0; j < NJ; j++) {
        int base = (j * 16 + l16) * (K * 2) + quad * 16;
        #pragma unroll
        for (int ks = 0; ks < KS; ks++) {
            int addr = (base + ks * 64) ^ (l16 << 4);
            bf16x8 b = *reinterpret_cast<const bf16x8*>(&lds[addr]);
            acc[j] = __builtin_amdgcn_mfma_f32_16x16x32_bf16(af[ks], b, acc[j], 0, 0, 0);
        }
    }

    // ---- epilogue
    #pragma unroll
    for (int j = 0; j < NJ; j++) {
        int c = colBase + j * 16 + l16;
        if (c >= NCtot) continue;
        if (c < split) {
            #pragma unroll
            for (int r = 0; r < 4; r++) {
                int row = rowBase + quad * 4 + r;
                if (row >= M) continue;
                float v = acc[j][r];
                if (outBf) outBf[(size_t)row * ldBf + c] = f2bf(v);
                if (outQ)  outQ[(size_t)row * ldBf + c] = f8enc(v);
            }
        } else if (c < split2) {
            float bv = biasSk[c - split];
            #pragma unroll
            for (int r = 0; r < 4; r++) {
                int row = rowBase + quad * 4 + r;
                if (row >= M) continue;
                outSk[(size_t)row * ldSk + (c - split)] = f2bf(acc[j][r] + bv);
            }
        } else {
            int a = c - split2;
            #pragma unroll
            for (int r = 0; r < 4; r++) {
                int row = rowBase + quad * 4 + r;
                if (row >= M) continue;
                float v = acc[j][r];
                if (NCtot - split2 == 16) {    // H=8: 8 as cols then 8 ad cols
                    if (a < 8) asOut[(size_t)row * 8 + a] = v;
                    else       adOut[(size_t)row * 8 + a - 8] = v;
                } else {                       // H=1: 1 as col, 1 ad col
                    if (a == 0) asOut[row] = v;
                    else        adOut[row] = v;
                }
            }
        }
    }
}

// ---------------------------------------------------------------- aggregation H=8,C=32 (fp8 gather, dwordx4)
// Per node: one wave. Gather layout: lane l reads uint4 (16 fp8 ch) at
// channel byte (l&15)*16 of row src(e), e = 4j + (l>>4). 8-edge chunks;
// rows prefetched 1 chunk ahead, esrc/weights 2 chunks ahead.
// NOTE: accumulators are four NAMED float4 (not an array) — dynamic
// indexing sends the array to scratch (rule #20; round-2 postmortem:
// 562 MB of scratch writes).
template <int MODE>
__global__ __launch_bounds__(256) void agg256(const unsigned char* __restrict__ hq,
                                              const float* __restrict__ as,
                                              const float* __restrict__ ad,
                                              const int* __restrict__ indptr,
                                              const int* __restrict__ esrc,
                                              const float* __restrict__ bias,
                                              const float* __restrict__ bn_g,
                                              const float* __restrict__ bn_b,
                                              const float* __restrict__ bn_m,
                                              const float* __restrict__ bn_v,
                                              const unsigned short* __restrict__ skip,
                                              unsigned short* __restrict__ out, int N) {
    int t = threadIdx.x;
    int n = blockIdx.x * 4 + (t >> 6);
    if (n >= N) return;
    int lane = t & 63;
    int e8 = lane >> 3, h8 = lane & 7;   // weight-round mapping: lane = e*8 + h
    int g4 = lane >> 4, cl = lane & 15;  // gather mapping
    int hd = cl >> 1;                    // head of my gathered channels
    int start = indptr[n], end = indptr[n + 1];
    int cnt = end - start;

    float adh = ad[n * 8 + h8];
    const unsigned char* hqc = hq + cl * 16;

    float4 acc0 = make_float4(0.f, 0.f, 0.f, 0.f);
    float4 acc1 = make_float4(0.f, 0.f, 0.f, 0.f);
    float4 acc2 = make_float4(0.f, 0.f, 0.f, 0.f);
    float4 acc3 = make_float4(0.f, 0.f, 0.f, 0.f);
    float sm = 0.f;
    int nfull = cnt & ~7;

    int sA = 0, sB = 0;
    float wA = 0.f, wB = 0.f;
    uint4 hv0 = {}, hv1 = {};
    if (nfull) {
        sA = esrc[start + e8];
        wA = __expf(lrelu(as[sA * 8 + h8] + adh));
        int r0 = __shfl(sA, g4 * 8);
        int r1 = __shfl(sA, (4 + g4) * 8);
        hv0 = *reinterpret_cast<const uint4*>(hqc + (size_t)r0 * 256);
        hv1 = *reinterpret_cast<const uint4*>(hqc + (size_t)r1 * 256);
        if (nfull > 8) {
            sB = esrc[start + 8 + e8];
            wB = __expf(lrelu(as[sB * 8 + h8] + adh));
        }
    }
    for (int i0 = start; i0 < start + nfull; i0 += 8) {
        uint4 u0 = hv0, u1 = hv1;
        float wcur = wA;
        // prefetch next chunk's rows (srcs sB already resident)
        if (i0 + 8 < start + nfull) {
            int r0 = __shfl(sB, g4 * 8);
            int r1 = __shfl(sB, (4 + g4) * 8);
            hv0 = *reinterpret_cast<const uint4*>(hqc + (size_t)r0 * 256);
            hv1 = *reinterpret_cast<const uint4*>(hqc + (size_t)r1 * 256);
        }
        // shift weight pipeline, prefetch srcs/weights 2 chunks ahead
        sA = sB; wA = wB;
        if (i0 + 16 < start + nfull) {
            sB = esrc[i0 + 16 + e8];
            wB = __expf(lrelu(as[sB * 8 + h8] + adh));
        }
        sm += wcur;
        float w0 = __shfl(wcur, g4 * 8 + hd);
        float w1 = __shfl(wcur, (4 + g4) * 8 + hd);
        fma_f8x4(w0, u0.x, acc0);
        fma_f8x4(w0, u0.y, acc1);
        fma_f8x4(w0, u0.z, acc2);
        fma_f8x4(w0, u0.w, acc3);
        fma_f8x4(w1, u1.x, acc0);
        fma_f8x4(w1, u1.y, acc1);
        fma_f8x4(w1, u1.z, acc2);
        fma_f8x4(w1, u1.w, acc3);
    }
    int rem = cnt - nfull;
    if (rem) {
        int i0 = start + nfull;
        int idx = i0 + e8;
        bool valid = idx < end;
        int s_r = esrc[valid ? idx : end - 1];
        float w_r = valid ? __expf(lrelu(as[s_r * 8 + h8] + adh)) : 0.f;
        sm += w_r;
        int r0 = __shfl(s_r, g4 * 8);                     // clamped rows (cache-hot)
        uint4 u0 = *reinterpret_cast<const uint4*>(hqc + (size_t)r0 * 256);
        float w0 = __shfl(w_r, g4 * 8 + hd);              // 0 for padded edges
        fma_f8x4(w0, u0.x, acc0);
        fma_f8x4(w0, u0.y, acc1);
        fma_f8x4(w0, u0.z, acc2);
        fma_f8x4(w0, u0.w, acc3);
        if (rem > 4) {
            int r1 = __shfl(s_r, (4 + g4) * 8);
            uint4 u1 = *reinterpret_cast<const uint4*>(hqc + (size_t)r1 * 256);
            float w1 = __shfl(w_r, (4 + g4) * 8 + hd);
            fma_f8x4(w1, u1.x, acc0);
            fma_f8x4(w1, u1.y, acc1);
            fma_f8x4(w1, u1.z, acc2);
            fma_f8x4(w1, u1.w, acc3);
        }
    }

    // combine the 4 edge-groups (all groups hold the same 16 channels)
    acc0.x += __shfl_xor(acc0.x, 16); acc0.y += __shfl_xor(acc0.y, 16);
    acc0.z += __shfl_xor(acc0.z, 16); acc0.w += __shfl_xor(acc0.w, 16);
    acc0.x += __shfl_xor(acc0.x, 32); acc0.y += __shfl_xor(acc0.y, 32);
    acc0.z += __shfl_xor(acc0.z, 32); acc0.w += __shfl_xor(acc0.w, 32);
    acc1.x += __shfl_xor(acc1.x, 16); acc1.y += __shfl_xor(acc1.y, 16);
    acc1.z += __shfl_xor(acc1.z, 16); acc1.w += __shfl_xor(acc1.w, 16);
    acc1.x += __shfl_xor(acc1.x, 32); acc1.y += __shfl_xor(acc1.y, 32);
    acc1.z += __shfl_xor(acc1.z, 32); acc1.w += __shfl_xor(acc1.w, 32);
    acc2.x += __shfl_xor(acc2.x, 16); acc2.y += __shfl_xor(acc2.y, 16);
    acc2.z += __shfl_xor(acc2.z, 16); acc2.w += __shfl_xor(acc2.w, 16);
    acc2.x += __shfl_xor(acc2.x, 32); acc2.y += __shfl_xor(acc2.y, 32);
    acc2.z += __shfl_xor(acc2.z, 32); acc2.w += __shfl_xor(acc2.w, 32);
    acc3.x += __shfl_xor(acc3.x, 16); acc3.y += __shfl_xor(acc3.y, 16);
    acc3.z += __shfl_xor(acc3.z, 16); acc3.w += __shfl_xor(acc3.w, 16);
    acc3.x += __shfl_xor(acc3.x, 32); acc3.y += __shfl_xor(acc3.y, 32);
    acc3.z += __shfl_xor(acc3.z, 32); acc3.w += __shfl_xor(acc3.w, 32);

    // per-head softmax denominators
    #pragma unroll
    for (int off = 8; off < 64; off <<= 1) sm += __shfl_xor(sm, off);
    float il = 1.f / (sm + 1e-16f);
    float il_c = __shfl(il, hd);

    // lane stores channel quarter cb = cl*16 + g4*4 (same head hd).
    // if/else over NAMED vars -> v_cndmask, no stack array.
    float4 my;
    if (g4 == 0)      my = acc0;
    else if (g4 == 1) my = acc1;
    else if (g4 == 2) my = acc2;
    else              my = acc3;
    int cb = cl * 16 + g4 * 4;

    float4 bv  = *reinterpret_cast<const float4*>(&bias[cb]);
    float4 gv  = *reinterpret_cast<const float4*>(&bn_g[cb]);
    float4 bbv = *reinterpret_cast<const float4*>(&bn_b[cb]);
    float4 mv  = *reinterpret_cast<const float4*>(&bn_m[cb]);
    float4 vv  = *reinterpret_cast<const float4*>(&bn_v[cb]);
    float o[4] = {my.x * il_c + bv.x, my.y * il_c + bv.y,
                  my.z * il_c + bv.z, my.w * il_c + bv.w};
    float g[4] = {gv.x, gv.y, gv.z, gv.w}, bb[4] = {bbv.x, bbv.y, bbv.z, bbv.w};
    float m[4] = {mv.x, mv.y, mv.z, mv.w}, vr[4] = {vv.x, vv.y, vv.z, vv.w};
    float sk[4] = {0.f, 0.f, 0.f, 0.f};
    if (MODE == 1) {
        ushort4 s4 = *reinterpret_cast<const ushort4*>(&skip[(size_t)n * 256 + cb]);
        sk[0] = bf2f(s4.x); sk[1] = bf2f(s4.y); sk[2] = bf2f(s4.z); sk[3] = bf2f(s4.w);
    }
    ushort4 res;
    unsigned short* rp = &res.x;
    #pragma unroll
    for (int j = 0; j < 4; j++) {
        float val = (o[j] - m[j]) * rsqrtf(vr[j] + BN_EPS) * g[j] + bb[j];
        val = val > 0.f ? val : (__expf(val) - 1.f);
        val += sk[j];
        rp[j] = f2bf(val);
    }
    *reinterpret_cast<ushort4*>(&out[(size_t)n * 256 + cb]) = res;
}

// ---------------------------------------------------------------- aggregation H=1,C=32
__global__ __launch_bounds__(256) void agg32(const unsigned short* __restrict__ h3,
                                             const float* __restrict__ as,
                                             const float* __restrict__ ad,
                                             const int* __restrict__ indptr,
                                             const int* __restrict__ esrc,
                                             const float* __restrict__ b3,
                                             const unsigned short* __restrict__ xs,
                                             float* __restrict__ out, int N) {
    int t = threadIdx.x;
    int n = blockIdx.x * 4 + (t >> 6);
    if (n >= N) return;
    int lane = t & 63;
    int e_sub = lane >> 3, c4 = (lane & 7) * 4;
    int start = indptr[n], end = indptr[n + 1];
    float adn = ad[n];

    float4 acc = make_float4(0.f, 0.f, 0.f, 0.f);
    float sm = 0.f;
    int i0 = start;
    for (; i0 + 16 <= end; i0 += 16) {
        int sA = esrc[i0 + e_sub];
        int sB = esrc[i0 + 8 + e_sub];
        float wA = __expf(lrelu(as[sA] + adn));
        float wB = __expf(lrelu(as[sB] + adn));
        sm += wA + wB;
        ushort4 hA = *reinterpret_cast<const ushort4*>(&h3[(size_t)sA * 32 + c4]);
        ushort4 hB = *reinterpret_cast<const ushort4*>(&h3[(size_t)sB * 32 + c4]);
        acc.x = fmaf(wA, bf2f(hA.x), acc.x); acc.y = fmaf(wA, bf2f(hA.y), acc.y);
        acc.z = fmaf(wA, bf2f(hA.z), acc.z); acc.w = fmaf(wA, bf2f(hA.w), acc.w);
        acc.x = fmaf(wB, bf2f(hB.x), acc.x); acc.y = fmaf(wB, bf2f(hB.y), acc.y);
        acc.z = fmaf(wB, bf2f(hB.z), acc.z); acc.w = fmaf(wB, bf2f(hB.w), acc.w);
    }
    for (; i0 < end; i0 += 8) {
        int idx = i0 + e_sub;
        bool valid = idx < end;
        if (valid) {
            int s = esrc[idx];
            float w = __expf(lrelu(as[s] + adn));
            sm += w;
            ushort4 hv = *reinterpret_cast<const ushort4*>(&h3[(size_t)s * 32 + c4]);
            acc.x = fmaf(w, bf2f(hv.x), acc.x);
            acc.y = fmaf(w, bf2f(hv.y), acc.y);
            acc.z = fmaf(w, bf2f(hv.z), acc.z);
            acc.w = fmaf(w, bf2f(hv.w), acc.w);
        }
    }
    #pragma unroll
    for (int off = 8; off < 64; off <<= 1) {
        sm    += __shfl_xor(sm, off);
        acc.x += __shfl_xor(acc.x, off);
        acc.y += __shfl_xor(acc.y, off);
        acc.z += __shfl_xor(acc.z, off);
        acc.w += __shfl_xor(acc.w, off);
    }
    if (e_sub == 0) {
        float il = 1.f / (sm + 1e-16f);
        float4 bv = *reinterpret_cast<const float4*>(&b3[c4]);
        ushort4 xv = *reinterpret_cast<const ushort4*>(&xs[(size_t)n * 32 + c4]);
        float4 o;
        o.x = acc.x * il + bv.x + bf2f(xv.x);
        o.y = acc.y * il + bv.y + bf2f(xv.y);
        o.z = acc.z * il + bv.z + bf2f(xv.z);
        o.w = acc.w * il + bv.w + bf2f(xv.w);
        *reinterpret_cast<float4*>(&out[(size_t)n * 32 + c4]) = o;
    }
}

// ---------------------------------------------------------------- launch
extern "C" void kernel_launch(void* const* d_in, const int* in_sizes, int n_in,
                              void* d_out, int out_size, void* d_ws, size_t ws_size,
                              hipStream_t stream) {
    const float* x      = (const float*)d_in[0];
    const int*   eidx   = (const int*)  d_in[1];
    const float* W1     = (const float*)d_in[2];
    const float* a_src1 = (const float*)d_in[3];
    const float* a_dst1 = (const float*)d_in[4];
    const float* b1     = (const float*)d_in[5];
    const float* bn1_g  = (const float*)d_in[6];
    const float* bn1_b  = (const float*)d_in[7];
    const float* bn1_m  = (const float*)d_in[8];
    const float* bn1_v  = (const float*)d_in[9];
    const float* W2     = (const float*)d_in[10];
    const float* a_src2 = (const float*)d_in[11];
    const float* a_dst2 = (const float*)d_in[12];
    const float* b2     = (const float*)d_in[13];
    const float* bn2_g  = (const float*)d_in[14];
    const float* bn2_b  = (const float*)d_in[15];
    const float* bn2_m  = (const float*)d_in[16];
    const float* bn2_v  = (const float*)d_in[17];
    const float* W3     = (const float*)d_in[18];
    const float* a_src3 = (const float*)d_in[19];
    const float* a_dst3 = (const float*)d_in[20];
    const float* b3     = (const float*)d_in[21];
    const float* Ws1    = (const float*)d_in[22];
    const float* bs1    = (const float*)d_in[23];
    const float* Ws2    = (const float*)d_in[24];
    const float* bs2    = (const float*)d_in[25];

    const int N = in_sizes[0] / 128;   // 50000
    const int E = in_sizes[1] / 2;     // 800000
    const int Etot = E + N;
    const int NB = (N + 255) >> 8;     // 196 buckets
    const int* srcl = eidx;
    const int* dstl = eidx + E;

    char* ws = (char*)d_ws;
    size_t off = 0;
    auto alloc = [&](size_t bytes) -> void* {
        void* p = ws + off;
        off += (bytes + 255) & ~(size_t)255;
        return p;
    };
    unsigned short* xb    = (unsigned short*)alloc((size_t)N * 128 * 2);
    unsigned short* feat  = (unsigned short*)alloc((size_t)N * 256 * 2); // x0 skip (bf16)
    unsigned char*  hq    = (unsigned char*)alloc((size_t)N * 256);     // fp8 h for gathers
    unsigned short* h2b   = (unsigned short*)alloc((size_t)N * 256 * 2); // layer-1 agg out
    unsigned short* featb = (unsigned short*)alloc((size_t)N * 256 * 2); // layer-2 agg out
    unsigned short* xsbuf = (unsigned short*)alloc((size_t)N * 32 * 2);  // xs skip (bf16)
    unsigned short* h3b   = (unsigned short*)alloc((size_t)N * 32 * 2);
    float*          asb   = (float*)alloc((size_t)N * 8 * 4);
    float*          adb   = (float*)alloc((size_t)N * 8 * 4);
    unsigned short* Wcat1 = (unsigned short*)alloc((size_t)640 * 128 * 2); // [W1t; Ws1t; Wa1] pad->640
    unsigned short* Wcat2 = (unsigned short*)alloc((size_t)320 * 256 * 2); // [W2t; Ws2t; Wa2] pad->320
    unsigned short* W3t   = (unsigned short*)alloc((size_t)64 * 256 * 2);  // [W3t; Wa3] pad->64
    int* gHC     = (int*)alloc(512 * 4);          // [gHist(256) | gCursor(256)]
    int* gHist   = gHC;
    int* gCursor = gHC + 256;
    unsigned int* bktEdges = (unsigned int*)alloc((size_t)Etot * 4);
    int* indptr  = (int*)alloc((size_t)(N + 1) * 4);
    int* esrc    = (int*)alloc((size_t)Etot * 4);
    (void)ws_size; (void)n_in; (void)out_size;

    // ---- CSR build (bucketed multi-split, scans recomputed locally)
    hipMemsetAsync(gHC, 0, 512 * 4, stream);
    int n4x = N * 128 / 4;
    int prepBlocks = (n4x + 154112 + 255) / 256;
    phase1<<<256 + prepBlocks, 256, 0, stream>>>(dstl, E, N, NB, gHist,
                                                 x, xb, n4x,
                                                 W1, Ws1, W2, Ws2, W3,
                                                 a_src1, a_dst1, a_src2, a_dst2,
                                                 a_src3, a_dst3,
                                                 Wcat1, Wcat2, W3t);
    bucket_scatter<<<(Etot + 4095) / 4096, 256, 0, stream>>>(srcl, dstl, E, N, NB,
                                                             gHist, gCursor, bktEdges);
    bucket_to_csr<<<NB, 256, 0, stream>>>(bktEdges, gHist, indptr, esrc, N, NB, Etot);

    int gy64 = (N + 63) / 64;          // 782 panel blocks
    int gn4 = (N + 3) / 4;

    // ---- layer 1: fused [h1 | x0 | alpha] = x @ [W1 | Ws1 | Wa1]
    gemm_panel<128, 128><<<dim3(gy64, 5), 256, 0, stream>>>(xb, Wcat1, nullptr, hq, feat, bs1,
                                                            asb, adb,
                                                            N, 528, 256, 512, 256, 256);
    agg256<1><<<gn4, 256, 0, stream>>>(hq, asb, adb, indptr, esrc, b1,
                                       bn1_g, bn1_b, bn1_m, bn1_v, feat, h2b, N);

    // ---- layer 2: fused [h2 | xs | alpha] = h @ [W2 | Ws2 | Wa2]
    gemm_panel<256, 64><<<dim3(gy64, 5), 256, 0, stream>>>(h2b, Wcat2, nullptr, hq, xsbuf, bs2,
                                                           asb, adb,
                                                           N, 304, 256, 288, 256, 32);
    agg256<0><<<gn4, 256, 0, stream>>>(hq, asb, adb, indptr, esrc, b2,
                                       bn2_g, bn2_b, bn2_m, bn2_v, nullptr, featb, N);

    // ---- layer 3: [h3 | alpha] = featb @ [W3t | Wa3]  (H=1)
    gemm_panel<256, 64><<<dim3(gy64, 1), 256, 0, stream>>>(featb, W3t, h3b, nullptr, nullptr, nullptr,
                                                           asb, adb,
                                                           N, 34, 32, 32, 32, 32);
    agg32<<<gn4, 256, 0, stream>>>(h3b, asb, adb, indptr, esrc, b3, xsbuf,
                                   (float*)d_out, N);
}